// Round 1
// baseline (627.820 us; speedup 1.0000x reference)
//
#include <hip/hip_runtime.h>
#include <hip/hip_bf16.h>

typedef __bf16 v8bf __attribute__((ext_vector_type(8)));
typedef float  v4f  __attribute__((ext_vector_type(4)));

__device__ __forceinline__ float lrelu02(float x){ return x > 0.f ? x : 0.2f*x; }

__device__ __forceinline__ unsigned short f2bf_rn(float f){
  unsigned int u = __float_as_uint(f);
  u += 0x7fffu + ((u >> 16) & 1u);
  return (unsigned short)(u >> 16);
}
__device__ __forceinline__ float bf2f(unsigned short h){
  return __uint_as_float(((unsigned int)h) << 16);
}

// ---------------- CSR build ----------------
__global__ void zero_int_kernel(int* p, int n){
  int i = blockIdx.x*blockDim.x + threadIdx.x;
  if (i < n) p[i] = 0;
}

__global__ void hist_kernel(const int* __restrict__ dst, int* counts, int E){
  int i = blockIdx.x*blockDim.x + threadIdx.x;
  if (i < E) atomicAdd(&counts[dst[i]], 1);
}

// single block, 1024 threads, n <= 8192
__global__ void scan_kernel(const int* __restrict__ counts, int* ptr, int* cursor, int n){
  __shared__ int sd[1024];
  int t = threadIdx.x;
  int base = t*8;
  int v[8]; int s = 0;
  #pragma unroll
  for (int i = 0; i < 8; ++i){ int x = (base+i < n) ? counts[base+i] : 0; v[i] = x; s += x; }
  sd[t] = s; __syncthreads();
  for (int off = 1; off < 1024; off <<= 1){
    int x = (t >= off) ? sd[t-off] : 0;
    __syncthreads();
    sd[t] += x;
    __syncthreads();
  }
  int run = sd[t] - s;
  #pragma unroll
  for (int i = 0; i < 8; ++i){
    if (base+i < n){ ptr[base+i] = run; cursor[base+i] = run; run += v[i]; }
  }
  if (t == 1023) ptr[n] = run;
}

__global__ void scatter_kernel(const int* __restrict__ src, const int* __restrict__ dst,
                               int* cursor, int* csr_src, int E){
  int i = blockIdx.x*blockDim.x + threadIdx.x;
  if (i < E){
    int p = atomicAdd(&cursor[dst[i]], 1);
    csr_src[p] = src[i];
  }
}

// ---------------- fp32 tiled GEMM ----------------
template<int BM,int BN,int BK,int TM,int TN>
__global__ __launch_bounds__(256) void gemm_tiled(const float* __restrict__ A,
    const float* __restrict__ B, float* __restrict__ C, int M, int N, int K){
  __shared__ float As[BK][BM+1];
  __shared__ float Bs[BK][BN+1];
  const int tid = threadIdx.x;
  const int tx = tid % (BN/TN);
  const int ty = tid / (BN/TN);
  const int brow = blockIdx.y*BM;
  const int bcol = blockIdx.x*BN;
  float acc[TM][TN] = {};
  for (int k0 = 0; k0 < K; k0 += BK){
    for (int i = tid; i < BM*BK; i += 256){
      int m = i / BK, kk = i % BK;
      As[kk][m] = A[(size_t)(brow+m)*K + k0 + kk];
    }
    for (int i = tid; i < BK*BN; i += 256){
      int kk = i / BN, nn = i % BN;
      Bs[kk][nn] = B[(size_t)(k0+kk)*N + bcol + nn];
    }
    __syncthreads();
    #pragma unroll
    for (int kk = 0; kk < BK; ++kk){
      float a[TM], b[TN];
      #pragma unroll
      for (int m = 0; m < TM; ++m) a[m] = As[kk][ty*TM+m];
      #pragma unroll
      for (int n = 0; n < TN; ++n) b[n] = Bs[kk][tx*TN+n];
      #pragma unroll
      for (int m = 0; m < TM; ++m)
        #pragma unroll
        for (int n = 0; n < TN; ++n) acc[m][n] += a[m]*b[n];
    }
    __syncthreads();
  }
  #pragma unroll
  for (int m = 0; m < TM; ++m)
    #pragma unroll
    for (int n = 0; n < TN; ++n)
      C[(size_t)(brow+ty*TM+m)*N + bcol+tx*TN+n] = acc[m][n];
}

// ---------------- per-node attention logits ----------------
__global__ void alpha_kernel(const float* __restrict__ h, const float* __restrict__ avs,
                             const float* __restrict__ avd, float* as_out, float* ad_out,
                             int n, int F){
  int wid = (blockIdx.x*blockDim.x + threadIdx.x) >> 6;
  int lane = threadIdx.x & 63;
  if (wid >= n) return;
  float ps = 0.f, pd = 0.f;
  for (int c = lane; c < F; c += 64){
    float hv = h[(size_t)wid*F + c];
    ps += hv * avs[c];
    pd += hv * avd[c];
  }
  for (int o = 32; o; o >>= 1){ ps += __shfl_xor(ps, o); pd += __shfl_xor(pd, o); }
  if (lane == 0){ as_out[wid] = ps; ad_out[wid] = pd; }
}

// ---------------- GAT softmax + aggregate (wave per node) ----------------
template<int FCH, bool ELU>
__global__ void gat_agg(const float* __restrict__ h, const float* __restrict__ as,
                        const float* __restrict__ ad, const int* __restrict__ ptr,
                        const int* __restrict__ csr_src, const float* __restrict__ bias,
                        float* __restrict__ out, int n){
  const int F = FCH*64;
  int wid = (blockIdx.x*blockDim.x + threadIdx.x) >> 6;
  int lane = threadIdx.x & 63;
  if (wid >= n) return;
  const int v = wid;
  const int beg = ptr[v], end = ptr[v+1];
  const float adv = ad[v];
  const float asv = as[v];
  // pass 1: segment max (includes self loop)
  float m = lrelu02(asv + adv);
  for (int j = beg + lane; j < end; j += 64)
    m = fmaxf(m, lrelu02(as[csr_src[j]] + adv));
  for (int o = 32; o; o >>= 1) m = fmaxf(m, __shfl_xor(m, o));
  // pass 2: accumulate exp(e-m)*h[src], sum of weights
  float acc0 = 0.f, acc1 = 0.f, ssum = 0.f;
  float wself = __expf(lrelu02(asv + adv) - m);
  if (lane == 0) ssum += wself;
  acc0 += wself * h[(size_t)v*F + lane];
  if (FCH == 2) acc1 += wself * h[(size_t)v*F + 64 + lane];
  for (int b0 = beg; b0 < end; b0 += 64){
    int j = b0 + lane;
    float wv = 0.f; int sv = 0;
    if (j < end){
      sv = csr_src[j];
      wv = __expf(lrelu02(as[sv] + adv) - m);
      ssum += wv;
    }
    int cnt = min(64, end - b0);
    for (int t = 0; t < cnt; ++t){
      float wt = __shfl(wv, t);
      int   st = __shfl(sv, t);
      acc0 += wt * h[(size_t)st*F + lane];
      if (FCH == 2) acc1 += wt * h[(size_t)st*F + 64 + lane];
    }
  }
  for (int o = 32; o; o >>= 1) ssum += __shfl_xor(ssum, o);
  float inv = 1.f / ssum;
  float r0 = acc0*inv + bias[lane];
  if (ELU) r0 = r0 > 0.f ? r0 : __expf(r0) - 1.f;
  out[(size_t)v*F + lane] = r0;
  if (FCH == 2){
    float r1 = acc1*inv + bias[64 + lane];
    if (ELU) r1 = r1 > 0.f ? r1 : __expf(r1) - 1.f;
    out[(size_t)v*F + 64 + lane] = r1;
  }
}

// ---------------- bf16 hi/lo split of z ----------------
__global__ void split_kernel(const float* __restrict__ z, unsigned short* hi,
                             unsigned short* lo, int n){
  int i = blockIdx.x*blockDim.x + threadIdx.x;
  if (i >= n) return;
  float f = z[i];
  unsigned short h = f2bf_rn(f);
  float rem = f - bf2f(h);
  hi[i] = h;
  lo[i] = f2bf_rn(rem);
}

// ---------------- A_pred = sigmoid(z z^T) via bf16-split MFMA ----------------
__device__ __forceinline__ v8bf ldz(const unsigned short* z, int node, int k){
  return *reinterpret_cast<const v8bf*>(z + ((size_t)node << 6) + k);
}

__global__ __launch_bounds__(256) void apred_kernel(const unsigned short* __restrict__ zhi,
    const unsigned short* __restrict__ zlo, float* __restrict__ out, int N){
  const int lane = threadIdx.x & 63;
  const int wave = threadIdx.x >> 6;
  const int i0 = blockIdx.y*64 + wave*16;
  const int j0 = blockIdx.x*64;
  const int r = lane & 15, q = lane >> 4;
  const int arow = i0 + r;
  // A fragments: A[m=lane&15][k=q*8+j]
  v8bf ahi0 = ldz(zhi, arow,      q*8);
  v8bf ahi1 = ldz(zhi, arow, 32 + q*8);
  v8bf alo0 = ldz(zlo, arow,      q*8);
  v8bf alo1 = ldz(zlo, arow, 32 + q*8);
  #pragma unroll
  for (int c = 0; c < 4; ++c){
    int brow = j0 + c*16 + r;   // B[k=q*8+j][n=lane&15] with B[k][n] = z[j0+n][k]
    v8bf bhi0 = ldz(zhi, brow,      q*8);
    v8bf bhi1 = ldz(zhi, brow, 32 + q*8);
    v8bf blo0 = ldz(zlo, brow,      q*8);
    v8bf blo1 = ldz(zlo, brow, 32 + q*8);
    v4f acc = {0.f,0.f,0.f,0.f};
    acc = __builtin_amdgcn_mfma_f32_16x16x32_bf16(ahi0, bhi0, acc, 0,0,0);
    acc = __builtin_amdgcn_mfma_f32_16x16x32_bf16(ahi1, bhi1, acc, 0,0,0);
    acc = __builtin_amdgcn_mfma_f32_16x16x32_bf16(ahi0, blo0, acc, 0,0,0);
    acc = __builtin_amdgcn_mfma_f32_16x16x32_bf16(ahi1, blo1, acc, 0,0,0);
    acc = __builtin_amdgcn_mfma_f32_16x16x32_bf16(alo0, bhi0, acc, 0,0,0);
    acc = __builtin_amdgcn_mfma_f32_16x16x32_bf16(alo1, bhi1, acc, 0,0,0);
    // C/D: col = lane&15, row = q*4 + reg
    float* op = out + (size_t)(i0 + q*4)*N + j0 + c*16 + r;
    #pragma unroll
    for (int t = 0; t < 4; ++t){
      float sg = 1.f / (1.f + __expf(-acc[t]));
      op[(size_t)t*N] = sg;
    }
  }
}

// ---------------- Student-t soft assignment q ----------------
__global__ void q_kernel(const float* __restrict__ z, const float* __restrict__ centers,
                         float* __restrict__ qout, int n, int K){
  int wid = (blockIdx.x*blockDim.x + threadIdx.x) >> 6;
  int lane = threadIdx.x & 63;
  if (wid >= n) return;
  float zv = z[(size_t)wid*64 + lane];
  float myq = 0.f, tot = 0.f;
  for (int k = 0; k < K; ++k){
    float d = zv - centers[k*64 + lane];
    float d2 = d*d;
    for (int o = 32; o; o >>= 1) d2 += __shfl_xor(d2, o);
    float qq = 1.f / (1.f + d2);     // wave-uniform after reduce
    if (lane == k) myq = qq;
    tot += qq;
  }
  if (lane < K) qout[(size_t)wid*K + lane] = myq / tot;
}

// ---------------- launch ----------------
extern "C" void kernel_launch(void* const* d_in, const int* in_sizes, int n_in,
                              void* d_out, int out_size, void* d_ws, size_t ws_size,
                              hipStream_t stream) {
  const float* x      = (const float*)d_in[0];
  const int*   ei     = (const int*)  d_in[1];
  const float* W1     = (const float*)d_in[2];
  const float* a_src1 = (const float*)d_in[3];
  const float* a_dst1 = (const float*)d_in[4];
  const float* b1     = (const float*)d_in[5];
  const float* W2     = (const float*)d_in[6];
  const float* a_src2 = (const float*)d_in[7];
  const float* a_dst2 = (const float*)d_in[8];
  const float* b2     = (const float*)d_in[9];
  const float* cent   = (const float*)d_in[10];

  const int H   = in_sizes[3];          // 128
  const int OUTF= in_sizes[7];          // 64
  const int INF = in_sizes[2] / H;      // 512
  const int N   = in_sizes[0] / INF;    // 8192
  const int E   = in_sizes[1] / 2;      // 262144
  const int K   = in_sizes[10] / OUTF;  // 16

  const int* e_src = ei;
  const int* e_dst = ei + E;

  // workspace (small arrays + bf16 z)
  char* wsp = (char*)d_ws;
  auto alloc = [&](size_t b)->void*{ void* p = (void*)wsp; wsp += (b + 255) & ~(size_t)255; return p; };
  int* counts   = (int*)alloc((size_t)N*4);
  int* ptr      = (int*)alloc((size_t)(N+1)*4);
  int* cursor   = (int*)alloc((size_t)N*4);
  int* csr_src  = (int*)alloc((size_t)E*4);
  float* as1    = (float*)alloc((size_t)N*4);
  float* ad1    = (float*)alloc((size_t)N*4);
  float* as2    = (float*)alloc((size_t)N*4);
  float* ad2    = (float*)alloc((size_t)N*4);
  unsigned short* zhi = (unsigned short*)alloc((size_t)N*OUTF*2);
  unsigned short* zlo = (unsigned short*)alloc((size_t)N*OUTF*2);

  // outputs; A_pred region doubles as scratch for intermediates (dead before apred)
  float* out_f  = (float*)d_out;
  float* z_out  = out_f;                              // [N, 64]
  float* ap_out = out_f + (size_t)N*OUTF;             // [N, N]
  float* q_out  = ap_out + (size_t)N*N;               // [N, K]
  float* h1  = ap_out;                                // [N,128]
  float* h2  = h1 + (size_t)N*H;                      // [N,128]
  float* h2w = h2 + (size_t)N*H;                      // [N,64]

  const int wavesPerGrid = (N*64 + 255)/256;

  zero_int_kernel<<<(N+255)/256, 256, 0, stream>>>(counts, N);
  gemm_tiled<64,64,16,4,4><<<dim3(H/64, N/64), 256, 0, stream>>>(x, W1, h1, N, H, INF);
  alpha_kernel<<<wavesPerGrid, 256, 0, stream>>>(h1, a_src1, a_dst1, as1, ad1, N, H);
  hist_kernel<<<(E+255)/256, 256, 0, stream>>>(e_dst, counts, E);
  scan_kernel<<<1, 1024, 0, stream>>>(counts, ptr, cursor, N);
  scatter_kernel<<<(E+255)/256, 256, 0, stream>>>(e_src, e_dst, cursor, csr_src, E);
  gat_agg<2,true><<<wavesPerGrid, 256, 0, stream>>>(h1, as1, ad1, ptr, csr_src, b1, h2, N);
  gemm_tiled<64,64,16,4,4><<<dim3(OUTF/64, N/64), 256, 0, stream>>>(h2, W2, h2w, N, OUTF, H);
  alpha_kernel<<<wavesPerGrid, 256, 0, stream>>>(h2w, a_src2, a_dst2, as2, ad2, N, OUTF);
  gat_agg<1,false><<<wavesPerGrid, 256, 0, stream>>>(h2w, as2, ad2, ptr, csr_src, b2, z_out, N);
  split_kernel<<<(N*OUTF+255)/256, 256, 0, stream>>>(z_out, zhi, zlo, N*OUTF);
  q_kernel<<<wavesPerGrid, 256, 0, stream>>>(z_out, cent, q_out, N, K);
  apred_kernel<<<dim3(N/64, N/64), 256, 0, stream>>>(zhi, zlo, ap_out, N);
}

// Round 2
// 565.067 us; speedup vs baseline: 1.1111x; 1.1111x over previous
//
#include <hip/hip_runtime.h>
#include <hip/hip_bf16.h>

typedef __bf16 v8bf __attribute__((ext_vector_type(8)));
typedef float  v4f  __attribute__((ext_vector_type(4)));

__device__ __forceinline__ float lrelu02(float x){ return x > 0.f ? x : 0.2f*x; }

__device__ __forceinline__ unsigned short f2bf_rn(float f){
  unsigned int u = __float_as_uint(f);
  u += 0x7fffu + ((u >> 16) & 1u);
  return (unsigned short)(u >> 16);
}
__device__ __forceinline__ float bf2f(unsigned short h){
  return __uint_as_float(((unsigned int)h) << 16);
}

// ---------------- CSR build ----------------
__global__ void zero_int_kernel(int* p, int n){
  int i = blockIdx.x*blockDim.x + threadIdx.x;
  if (i < n) p[i] = 0;
}

__global__ void hist_kernel(const int* __restrict__ dst, int* counts, int E){
  int i = blockIdx.x*blockDim.x + threadIdx.x;
  if (i < E) atomicAdd(&counts[dst[i]], 1);
}

// single block, 1024 threads, n <= 8192
__global__ void scan_kernel(const int* __restrict__ counts, int* ptr, int* cursor, int n){
  __shared__ int sd[1024];
  int t = threadIdx.x;
  int base = t*8;
  int v[8]; int s = 0;
  #pragma unroll
  for (int i = 0; i < 8; ++i){ int x = (base+i < n) ? counts[base+i] : 0; v[i] = x; s += x; }
  sd[t] = s; __syncthreads();
  for (int off = 1; off < 1024; off <<= 1){
    int x = (t >= off) ? sd[t-off] : 0;
    __syncthreads();
    sd[t] += x;
    __syncthreads();
  }
  int run = sd[t] - s;
  #pragma unroll
  for (int i = 0; i < 8; ++i){
    if (base+i < n){ ptr[base+i] = run; cursor[base+i] = run; run += v[i]; }
  }
  if (t == 1023) ptr[n] = run;
}

__global__ void scatter_kernel(const int* __restrict__ src, const int* __restrict__ dst,
                               int* cursor, int* csr_src, int E){
  int i = blockIdx.x*blockDim.x + threadIdx.x;
  if (i < E){
    int p = atomicAdd(&cursor[dst[i]], 1);
    csr_src[p] = src[i];
  }
}

// ---------------- bf16 hi/lo split of x + split/transpose of W1 ----------------
__global__ void convert_kernel(const float* __restrict__ x, const float* __restrict__ W1,
    unsigned short* xh, unsigned short* xl, unsigned short* wth, unsigned short* wtl,
    int nx, int nw){
  int i = blockIdx.x*blockDim.x + threadIdx.x;
  if (i < nx){
    float f = x[i];
    unsigned short h = f2bf_rn(f);
    xh[i] = h;
    xl[i] = f2bf_rn(f - bf2f(h));
  } else if (i < nx + nw){
    int e = i - nx;
    int k = e >> 7, n = e & 127;           // W1 is [512,128] row-major
    float f = W1[e];
    unsigned short h = f2bf_rn(f);
    wth[n*512 + k] = h;                     // transposed: Wt[n][k]
    wtl[n*512 + k] = f2bf_rn(f - bf2f(h));
  }
}

// ---------------- GEMM1: h1 = x @ W1 via bf16-split MFMA ----------------
// block = 128 threads (2 waves), wave covers 16 rows x 128 cols; grid = M/32
__global__ __launch_bounds__(128) void gemm1_mfma(const unsigned short* __restrict__ xh,
    const unsigned short* __restrict__ xl, const unsigned short* __restrict__ wth,
    const unsigned short* __restrict__ wtl, float* __restrict__ h1){
  const int lane = threadIdx.x & 63;
  const int wave = threadIdx.x >> 6;
  const int i0 = blockIdx.x*32 + wave*16;
  const int r = lane & 15, q = lane >> 4;
  const unsigned short* xrh = xh + (size_t)(i0 + r)*512;
  const unsigned short* xrl = xl + (size_t)(i0 + r)*512;
  v4f acc[8];
  #pragma unroll
  for (int c = 0; c < 8; ++c) acc[c] = (v4f){0.f,0.f,0.f,0.f};
  for (int kt = 0; kt < 16; ++kt){
    int k = kt*32 + q*8;
    v8bf ah = *reinterpret_cast<const v8bf*>(xrh + k);
    v8bf al = *reinterpret_cast<const v8bf*>(xrl + k);
    #pragma unroll
    for (int ct = 0; ct < 8; ++ct){
      v8bf bh = *reinterpret_cast<const v8bf*>(wth + (size_t)(ct*16 + r)*512 + k);
      v8bf bl = *reinterpret_cast<const v8bf*>(wtl + (size_t)(ct*16 + r)*512 + k);
      acc[ct] = __builtin_amdgcn_mfma_f32_16x16x32_bf16(ah, bh, acc[ct], 0,0,0);
      acc[ct] = __builtin_amdgcn_mfma_f32_16x16x32_bf16(al, bh, acc[ct], 0,0,0);
      acc[ct] = __builtin_amdgcn_mfma_f32_16x16x32_bf16(ah, bl, acc[ct], 0,0,0);
    }
  }
  // C/D: col = ct*16 + (lane&15), row = i0 + q*4 + t
  #pragma unroll
  for (int ct = 0; ct < 8; ++ct)
    #pragma unroll
    for (int t = 0; t < 4; ++t)
      h1[(size_t)(i0 + q*4 + t)*128 + ct*16 + r] = acc[ct][t];
}

// ---------------- fp32 tiled GEMM (layer-2 feature transform) ----------------
template<int BM,int BN,int BK,int TM,int TN>
__global__ __launch_bounds__(256) void gemm_tiled(const float* __restrict__ A,
    const float* __restrict__ B, float* __restrict__ C, int M, int N, int K){
  __shared__ float As[BK][BM+1];
  __shared__ float Bs[BK][BN+1];
  const int tid = threadIdx.x;
  const int tx = tid % (BN/TN);
  const int ty = tid / (BN/TN);
  const int brow = blockIdx.y*BM;
  const int bcol = blockIdx.x*BN;
  float acc[TM][TN] = {};
  for (int k0 = 0; k0 < K; k0 += BK){
    for (int i = tid; i < BM*BK; i += 256){
      int m = i / BK, kk = i % BK;
      As[kk][m] = A[(size_t)(brow+m)*K + k0 + kk];
    }
    for (int i = tid; i < BK*BN; i += 256){
      int kk = i / BN, nn = i % BN;
      Bs[kk][nn] = B[(size_t)(k0+kk)*N + bcol + nn];
    }
    __syncthreads();
    #pragma unroll
    for (int kk = 0; kk < BK; ++kk){
      float a[TM], b[TN];
      #pragma unroll
      for (int m = 0; m < TM; ++m) a[m] = As[kk][ty*TM+m];
      #pragma unroll
      for (int n = 0; n < TN; ++n) b[n] = Bs[kk][tx*TN+n];
      #pragma unroll
      for (int m = 0; m < TM; ++m)
        #pragma unroll
        for (int n = 0; n < TN; ++n) acc[m][n] += a[m]*b[n];
    }
    __syncthreads();
  }
  #pragma unroll
  for (int m = 0; m < TM; ++m)
    #pragma unroll
    for (int n = 0; n < TN; ++n)
      C[(size_t)(brow+ty*TM+m)*N + bcol+tx*TN+n] = acc[m][n];
}

// ---------------- per-node attention logits ----------------
__global__ void alpha_kernel(const float* __restrict__ h, const float* __restrict__ avs,
                             const float* __restrict__ avd, float* as_out, float* ad_out,
                             int n, int F){
  int wid = (blockIdx.x*blockDim.x + threadIdx.x) >> 6;
  int lane = threadIdx.x & 63;
  if (wid >= n) return;
  float ps = 0.f, pd = 0.f;
  for (int c = lane; c < F; c += 64){
    float hv = h[(size_t)wid*F + c];
    ps += hv * avs[c];
    pd += hv * avd[c];
  }
  for (int o = 32; o; o >>= 1){ ps += __shfl_xor(ps, o); pd += __shfl_xor(pd, o); }
  if (lane == 0){ as_out[wid] = ps; ad_out[wid] = pd; }
}

// ---------------- GAT layer 1: softmax + aggregate (wave per node) ----------------
__global__ void gat_agg1(const float* __restrict__ h, const float* __restrict__ as,
                         const float* __restrict__ ad, const int* __restrict__ ptr,
                         const int* __restrict__ csr_src, const float* __restrict__ bias,
                         float* __restrict__ out, int n){
  const int F = 128;
  int wid = (blockIdx.x*blockDim.x + threadIdx.x) >> 6;
  int lane = threadIdx.x & 63;
  if (wid >= n) return;
  const int v = wid;
  const int beg = ptr[v], end = ptr[v+1];
  const float adv = ad[v];
  const float asv = as[v];
  float m = lrelu02(asv + adv);
  for (int j = beg + lane; j < end; j += 64)
    m = fmaxf(m, lrelu02(as[csr_src[j]] + adv));
  for (int o = 32; o; o >>= 1) m = fmaxf(m, __shfl_xor(m, o));
  float acc0 = 0.f, acc1 = 0.f, ssum = 0.f;
  float wself = __expf(lrelu02(asv + adv) - m);
  if (lane == 0) ssum += wself;
  acc0 += wself * h[(size_t)v*F + lane];
  acc1 += wself * h[(size_t)v*F + 64 + lane];
  for (int b0 = beg; b0 < end; b0 += 64){
    int j = b0 + lane;
    float wv = 0.f; int sv = 0;
    if (j < end){
      sv = csr_src[j];
      wv = __expf(lrelu02(as[sv] + adv) - m);
      ssum += wv;
    }
    int cnt = min(64, end - b0);
    for (int t = 0; t < cnt; ++t){
      float wt = __shfl(wv, t);
      int   st = __shfl(sv, t);
      acc0 += wt * h[(size_t)st*F + lane];
      acc1 += wt * h[(size_t)st*F + 64 + lane];
    }
  }
  for (int o = 32; o; o >>= 1) ssum += __shfl_xor(ssum, o);
  float inv = 1.f / ssum;
  float r0 = acc0*inv + bias[lane];
  r0 = r0 > 0.f ? r0 : __expf(r0) - 1.f;   // ELU
  out[(size_t)v*F + lane] = r0;
  float r1 = acc1*inv + bias[64 + lane];
  r1 = r1 > 0.f ? r1 : __expf(r1) - 1.f;
  out[(size_t)v*F + 64 + lane] = r1;
}

// ---------------- GAT layer 2 + z-split + Student-t q (fused) ----------------
__global__ void gat_agg2_fused(const float* __restrict__ h, const float* __restrict__ as,
                               const float* __restrict__ ad, const int* __restrict__ ptr,
                               const int* __restrict__ csr_src, const float* __restrict__ bias,
                               const float* __restrict__ centers,
                               float* __restrict__ z_out, unsigned short* __restrict__ zhi,
                               unsigned short* __restrict__ zlo, float* __restrict__ qout,
                               int n, int K){
  const int F = 64;
  int wid = (blockIdx.x*blockDim.x + threadIdx.x) >> 6;
  int lane = threadIdx.x & 63;
  if (wid >= n) return;
  const int v = wid;
  const int beg = ptr[v], end = ptr[v+1];
  const float adv = ad[v];
  const float asv = as[v];
  float m = lrelu02(asv + adv);
  for (int j = beg + lane; j < end; j += 64)
    m = fmaxf(m, lrelu02(as[csr_src[j]] + adv));
  for (int o = 32; o; o >>= 1) m = fmaxf(m, __shfl_xor(m, o));
  float acc0 = 0.f, ssum = 0.f;
  float wself = __expf(lrelu02(asv + adv) - m);
  if (lane == 0) ssum += wself;
  acc0 += wself * h[(size_t)v*F + lane];
  for (int b0 = beg; b0 < end; b0 += 64){
    int j = b0 + lane;
    float wv = 0.f; int sv = 0;
    if (j < end){
      sv = csr_src[j];
      wv = __expf(lrelu02(as[sv] + adv) - m);
      ssum += wv;
    }
    int cnt = min(64, end - b0);
    for (int t = 0; t < cnt; ++t){
      float wt = __shfl(wv, t);
      int   st = __shfl(sv, t);
      acc0 += wt * h[(size_t)st*F + lane];
    }
  }
  for (int o = 32; o; o >>= 1) ssum += __shfl_xor(ssum, o);
  float r0 = acc0 / ssum + bias[lane];     // z row, one float per lane
  z_out[(size_t)v*F + lane] = r0;
  unsigned short hh = f2bf_rn(r0);
  zhi[(size_t)v*F + lane] = hh;
  zlo[(size_t)v*F + lane] = f2bf_rn(r0 - bf2f(hh));
  // Student-t q
  float myq = 0.f, tot = 0.f;
  for (int k = 0; k < K; ++k){
    float d = r0 - centers[k*F + lane];
    float d2 = d*d;
    for (int o = 32; o; o >>= 1) d2 += __shfl_xor(d2, o);
    float qq = 1.f / (1.f + d2);
    if (lane == k) myq = qq;
    tot += qq;
  }
  if (lane < K) qout[(size_t)v*K + lane] = myq / tot;
}

// ---------------- A_pred = sigmoid(z z^T) via bf16-split MFMA ----------------
__device__ __forceinline__ v8bf ldz(const unsigned short* z, int node, int k){
  return *reinterpret_cast<const v8bf*>(z + ((size_t)node << 6) + k);
}

__global__ __launch_bounds__(256) void apred_kernel(const unsigned short* __restrict__ zhi,
    const unsigned short* __restrict__ zlo, float* __restrict__ out, int N){
  __shared__ float tile[4][16][68];        // per-wave private 16x64 (+4 pad)
  const int lane = threadIdx.x & 63;
  const int wave = threadIdx.x >> 6;
  const int i0 = blockIdx.y*64 + wave*16;
  const int j0 = blockIdx.x*64;
  const int r = lane & 15, q = lane >> 4;
  const int arow = i0 + r;
  v8bf ahi0 = ldz(zhi, arow,      q*8);
  v8bf ahi1 = ldz(zhi, arow, 32 + q*8);
  v8bf alo0 = ldz(zlo, arow,      q*8);
  v8bf alo1 = ldz(zlo, arow, 32 + q*8);
  #pragma unroll
  for (int c = 0; c < 4; ++c){
    int brow = j0 + c*16 + r;
    v8bf bhi0 = ldz(zhi, brow,      q*8);
    v8bf bhi1 = ldz(zhi, brow, 32 + q*8);
    v8bf blo0 = ldz(zlo, brow,      q*8);
    v8bf blo1 = ldz(zlo, brow, 32 + q*8);
    v4f acc = {0.f,0.f,0.f,0.f};
    acc = __builtin_amdgcn_mfma_f32_16x16x32_bf16(ahi0, bhi0, acc, 0,0,0);
    acc = __builtin_amdgcn_mfma_f32_16x16x32_bf16(ahi1, bhi1, acc, 0,0,0);
    acc = __builtin_amdgcn_mfma_f32_16x16x32_bf16(ahi0, blo0, acc, 0,0,0);
    acc = __builtin_amdgcn_mfma_f32_16x16x32_bf16(ahi1, blo1, acc, 0,0,0);
    acc = __builtin_amdgcn_mfma_f32_16x16x32_bf16(alo0, bhi0, acc, 0,0,0);
    acc = __builtin_amdgcn_mfma_f32_16x16x32_bf16(alo1, bhi1, acc, 0,0,0);
    // C/D: col = lane&15, row = q*4 + t  -> sigmoid -> LDS (wave-private, no barrier)
    #pragma unroll
    for (int t = 0; t < 4; ++t){
      float e = __expf(-acc[t]);
      tile[wave][q*4 + t][c*16 + r] = __builtin_amdgcn_rcpf(1.f + e);
    }
  }
  // store: each instr writes 4 full 256B-contiguous rows (16 lanes x float4 per row)
  #pragma unroll
  for (int t = 0; t < 4; ++t){
    int row = t*4 + (lane >> 4);
    int col = (lane & 15)*4;
    v4f vv = *reinterpret_cast<v4f*>(&tile[wave][row][col]);
    *reinterpret_cast<v4f*>(out + (size_t)(i0 + row)*N + j0 + col) = vv;
  }
}

// ---------------- launch ----------------
extern "C" void kernel_launch(void* const* d_in, const int* in_sizes, int n_in,
                              void* d_out, int out_size, void* d_ws, size_t ws_size,
                              hipStream_t stream) {
  const float* x      = (const float*)d_in[0];
  const int*   ei     = (const int*)  d_in[1];
  const float* W1     = (const float*)d_in[2];
  const float* a_src1 = (const float*)d_in[3];
  const float* a_dst1 = (const float*)d_in[4];
  const float* b1     = (const float*)d_in[5];
  const float* W2     = (const float*)d_in[6];
  const float* a_src2 = (const float*)d_in[7];
  const float* a_dst2 = (const float*)d_in[8];
  const float* b2     = (const float*)d_in[9];
  const float* cent   = (const float*)d_in[10];

  const int H   = in_sizes[3];          // 128
  const int OUTF= in_sizes[7];          // 64
  const int INF = in_sizes[2] / H;      // 512
  const int N   = in_sizes[0] / INF;    // 8192
  const int E   = in_sizes[1] / 2;      // 262144
  const int K   = in_sizes[10] / OUTF;  // 16

  const int* e_src = ei;
  const int* e_dst = ei + E;

  char* wsp = (char*)d_ws;
  auto alloc = [&](size_t b)->void*{ void* p = (void*)wsp; wsp += (b + 255) & ~(size_t)255; return p; };
  int* counts   = (int*)alloc((size_t)N*4);
  int* ptr      = (int*)alloc((size_t)(N+1)*4);
  int* cursor   = (int*)alloc((size_t)N*4);
  int* csr_src  = (int*)alloc((size_t)E*4);
  float* as1    = (float*)alloc((size_t)N*4);
  float* ad1    = (float*)alloc((size_t)N*4);
  float* as2    = (float*)alloc((size_t)N*4);
  float* ad2    = (float*)alloc((size_t)N*4);
  unsigned short* zhi = (unsigned short*)alloc((size_t)N*OUTF*2);
  unsigned short* zlo = (unsigned short*)alloc((size_t)N*OUTF*2);
  unsigned short* xh  = (unsigned short*)alloc((size_t)N*INF*2);
  unsigned short* xl  = (unsigned short*)alloc((size_t)N*INF*2);
  unsigned short* wth = (unsigned short*)alloc((size_t)INF*H*2);
  unsigned short* wtl = (unsigned short*)alloc((size_t)INF*H*2);

  float* out_f  = (float*)d_out;
  float* z_out  = out_f;                              // [N, 64]
  float* ap_out = out_f + (size_t)N*OUTF;             // [N, N]
  float* q_out  = ap_out + (size_t)N*N;               // [N, K]
  float* h1  = ap_out;                                // scratch (dead before apred)
  float* h2  = h1 + (size_t)N*H;
  float* h2w = h2 + (size_t)N*H;

  const int wavesPerGrid = (N*64 + 255)/256;
  const int nx = N*INF, nw = INF*H;

  zero_int_kernel<<<(N+255)/256, 256, 0, stream>>>(counts, N);
  hist_kernel<<<(E+255)/256, 256, 0, stream>>>(e_dst, counts, E);
  scan_kernel<<<1, 1024, 0, stream>>>(counts, ptr, cursor, N);
  scatter_kernel<<<(E+255)/256, 256, 0, stream>>>(e_src, e_dst, cursor, csr_src, E);
  convert_kernel<<<(nx+nw+255)/256, 256, 0, stream>>>(x, W1, xh, xl, wth, wtl, nx, nw);
  gemm1_mfma<<<N/32, 128, 0, stream>>>(xh, xl, wth, wtl, h1);
  alpha_kernel<<<wavesPerGrid, 256, 0, stream>>>(h1, a_src1, a_dst1, as1, ad1, N, H);
  gat_agg1<<<wavesPerGrid, 256, 0, stream>>>(h1, as1, ad1, ptr, csr_src, b1, h2, N);
  gemm_tiled<64,64,16,4,4><<<dim3(OUTF/64, N/64), 256, 0, stream>>>(h2, W2, h2w, N, OUTF, H);
  alpha_kernel<<<wavesPerGrid, 256, 0, stream>>>(h2w, a_src2, a_dst2, as2, ad2, N, OUTF);
  gat_agg2_fused<<<wavesPerGrid, 256, 0, stream>>>(h2w, as2, ad2, ptr, csr_src, b2, cent,
                                                   z_out, zhi, zlo, q_out, N, K);
  apred_kernel<<<dim3(N/64, N/64), 256, 0, stream>>>(zhi, zlo, ap_out, N);
}